// Round 8
// baseline (150.476 us; speedup 1.0000x reference)
//
#include <hip/hip_runtime.h>
#include <math.h>

// N=8192, D=256. sim = normed @ normed^T; four reductions fused, sim never materialized.
// fp16 split: x = h + l, A2 = [H|L] (8192 x 512 fp16). A2·A2^T = HH^T + LL^T.
#define NROWS 8192
#define DIM   256
#define K2    512                  // fp16 elems per row (1024 B)
#define NTB   64                   // 8192/128 tiles per side
#define NTRI  2080                 // NTB*(NTB+1)/2 lower-tri tiles; 2080 = 8*260
#define SIM_THR 0.85f

#define A2_OFF   1024
#define EDGE_OFF (1024 + NROWS * K2 * 2)

typedef _Float16 half8 __attribute__((ext_vector_type(8)));
typedef float f32x4 __attribute__((ext_vector_type(4)));

__device__ inline void load_lds16(const void* g, void* l) {
    __builtin_amdgcn_global_load_lds((const __attribute__((address_space(1))) void*)g,
                                     (__attribute__((address_space(3))) void*)l, 16, 0, 0);
}

__device__ inline void atomicMaxF(float* addr, float val) {
    if (val >= 0.f) atomicMax((int*)addr, __float_as_int(val));
    else            atomicMin((unsigned int*)addr, __float_as_uint(val));
}

// One wave per row: normalize (fp32), split to fp16 h/l, write A2 = [H|L].
__global__ __launch_bounds__(256) void prep_kernel(const float* __restrict__ x,
                                                   unsigned short* __restrict__ a2,
                                                   float* wsf) {
    if (blockIdx.x == 0 && threadIdx.x == 0) {
        wsf[0] = -INFINITY; wsf[1] = 0.f;
        ((unsigned int*)wsf)[2] = 0u; ((unsigned int*)wsf)[3] = 0u;
    }
    int row  = blockIdx.x * 4 + (threadIdx.x >> 6);
    int lane = threadIdx.x & 63;
    float4 v = ((const float4*)(x + (size_t)row * DIM))[lane];
    float ss = v.x * v.x + v.y * v.y + v.z * v.z + v.w * v.w;
    #pragma unroll
    for (int off = 32; off; off >>= 1) ss += __shfl_xor(ss, off);
    float norm = fmaxf(sqrtf(ss), 1e-12f);
    float f[4] = {v.x / norm, v.y / norm, v.z / norm, v.w / norm};
    unsigned short h[4], l[4];
    #pragma unroll
    for (int j = 0; j < 4; ++j) {
        _Float16 hh = (_Float16)f[j];
        _Float16 ll = (_Float16)(f[j] - (float)hh);
        h[j] = __builtin_bit_cast(unsigned short, hh);
        l[j] = __builtin_bit_cast(unsigned short, ll);
    }
    unsigned short* rp = a2 + (size_t)row * K2;
    *(ushort4*)(rp + lane * 4)       = make_ushort4(h[0], h[1], h[2], h[3]);
    *(ushort4*)(rp + DIM + lane * 4) = make_ushort4(l[0], l[1], l[2], l[3]);
}

// 128x128 tile per block (lower-tri tiles), 256 threads = 4 waves (2x2), wave-tile
// 64x64, mfma_f32_16x16x32_f16.
// Structure: m97-proven geometry + double-buffered LDS (64 KB -> 2 blocks/CU for
// cross-block TLP overlap, m114) + counted s_waitcnt vmcnt(8) (t+1's 8 loads stay
// in flight across the barrier; only drained on final iter) + ONE barrier pair per
// K-iter. Grid 2080 = 8*260: bijective XCD swizzle, ~4.06 co-resident rounds
// (tail ~2% vs 31% at 256^2).
__global__ __launch_bounds__(256, 2) void sim_kernel(const unsigned short* __restrict__ a2,
                                                     float* wsf, int2* edges, int cap) {
    int bid = blockIdx.x;
    int idx = (bid & 7) * (NTRI / 8) + (bid >> 3);   // contiguous tri-chunk per XCD
    int bi = (int)((sqrtf(8.f * idx + 1.f) - 1.f) * 0.5f);
    while ((bi + 1) * (bi + 2) / 2 <= idx) ++bi;
    while (bi * (bi + 1) / 2 > idx) --bi;
    int bj = idx - bi * (bi + 1) / 2;          // bj <= bi
    int i0 = bi * 128, j0 = bj * 128;

    __shared__ __align__(16) char As[2][128 * 128];   // 16 KB each
    __shared__ __align__(16) char Bs[2][128 * 128];
    __shared__ float sred[12];

    int t = threadIdx.x, lane = t & 63, w = t >> 6;   // w: 0..3
    int wr = w >> 1, wc = w & 1;                       // 2x2 wave grid

    f32x4 acc[4][4] = {};

    // staging: wave w stages rows [w*32, w*32+32) of A and B; 4 calls each,
    // lane i -> row +(i>>3), global col-bytes ((i&7)^(i>>3))*16 (inverse swizzle),
    // LDS dest linear (gload_lds writes base + lane*16). Verified conflict-free (r2/r5).
    int perm = ((lane & 7) ^ (lane >> 3)) * 16;
    const char* gA = (const char*)a2 + (size_t)(i0 + w * 32 + (lane >> 3)) * 1024 + perm;
    const char* gB = (const char*)a2 + (size_t)(j0 + w * 32 + (lane >> 3)) * 1024 + perm;
    int ldsW = w * 32 * 128;                           // wave's 32-row slab

    int rbA = (wr * 64 + (lane & 15)) * 128;           // frag row base (bytes)
    int rbB = (wc * 64 + (lane & 15)) * 128;
    int kx  = (lane & 7) << 4;                         // read-side XOR (row&7 of read row)
    int kb0 = (lane >> 4) << 4;                        // k-group byte offset

    // prologue: stage K-tile 0 into buffer 0 (8 loads in flight per wave)
    #pragma unroll
    for (int q = 0; q < 4; ++q) {
        load_lds16(gA + q * 8192, As[0] + ldsW + q * 1024);
        load_lds16(gB + q * 8192, Bs[0] + ldsW + q * 1024);
    }

    for (int it = 0; it < 8; ++it) {                   // K = 512 elems = 8 K-tiles
        int c = it & 1;
        if (it < 7) {
            int kc = (it + 1) * 128;
            #pragma unroll
            for (int q = 0; q < 4; ++q) {
                load_lds16(gA + kc + q * 8192, As[c ^ 1] + ldsW + q * 1024);
                load_lds16(gB + kc + q * 8192, Bs[c ^ 1] + ldsW + q * 1024);
            }
            asm volatile("s_waitcnt vmcnt(8)" ::: "memory");   // t's 8 done; t+1's in flight
        } else {
            asm volatile("s_waitcnt vmcnt(0)" ::: "memory");   // final tile: drain
        }
        __builtin_amdgcn_s_barrier();                  // all waves' t-data visible

        const char* A = As[c];
        const char* B = Bs[c];
        __builtin_amdgcn_s_setprio(1);
        #pragma unroll
        for (int ks = 0; ks < 2; ++ks) {
            int kb = (ks * 64 + kb0) ^ kx;
            half8 af[4], bf[4];
            #pragma unroll
            for (int m = 0; m < 4; ++m) {
                af[m] = *(const half8*)(A + rbA + m * 2048 + kb);
                bf[m] = *(const half8*)(B + rbB + m * 2048 + kb);
            }
            #pragma unroll
            for (int m = 0; m < 4; ++m)
                #pragma unroll
                for (int n = 0; n < 4; ++n)
                    acc[m][n] = __builtin_amdgcn_mfma_f32_16x16x32_f16(af[m], bf[n], acc[m][n], 0, 0, 0);
        }
        __builtin_amdgcn_s_setprio(0);
        __builtin_amdgcn_s_barrier();                  // reads of buf c retired before
                                                       // iter t+1 overwrites it
    }

    // fused epilogue: C/D layout col=lane&15, row=(lane>>4)*4+reg (m89-verified, r2-proven)
    bool diagT = (bi == bj);
    float        wgt  = diagT ? 1.f : 2.f;
    unsigned int wgtu = diagT ? 1u : 2u;
    float lmax = -INFINITY, lsum = 0.f;
    unsigned int lcnt = 0;
    #pragma unroll
    for (int m = 0; m < 4; ++m) {
        #pragma unroll
        for (int n = 0; n < 4; ++n) {
            #pragma unroll
            for (int j = 0; j < 4; ++j) {
                float s = acc[m][n][j];
                int gi = i0 + wr * 64 + m * 16 + (lane >> 4) * 4 + j;
                int gj = j0 + wc * 64 + n * 16 + (lane & 15);
                if (gi != gj) {
                    lmax = fmaxf(lmax, s);
                    lsum += s;
                    if (s > SIM_THR) {
                        lcnt++;
                        unsigned int e = atomicAdd(&((unsigned int*)wsf)[3], 1u);
                        if (e < (unsigned int)cap) edges[e] = make_int2(gi, gj);
                    }
                }
            }
        }
    }
    #pragma unroll
    for (int off = 32; off; off >>= 1) {
        lmax = fmaxf(lmax, __shfl_xor(lmax, off));
        lsum += __shfl_xor(lsum, off);
        lcnt += __shfl_xor(lcnt, off);
    }
    if (lane == 0) { sred[w] = lmax; sred[4 + w] = lsum; ((unsigned int*)sred)[8 + w] = lcnt; }
    __syncthreads();
    if (t == 0) {
        float bm = fmaxf(fmaxf(sred[0], sred[1]), fmaxf(sred[2], sred[3]));
        float bs = sred[4] + sred[5] + sred[6] + sred[7];
        unsigned int bc = ((unsigned int*)sred)[8] + ((unsigned int*)sred)[9]
                        + ((unsigned int*)sred)[10] + ((unsigned int*)sred)[11];
        atomicMaxF(&wsf[0], bm);
        atomicAdd(&wsf[1], bs * wgt);
        if (bc) atomicAdd(&((unsigned int*)wsf)[2], bc * wgtu);
    }
}

// Single block: reference's exact 16-iter min-label + pointer-jump (LDS labels),
// early-exit when no edges (labels provably stay identity), then features + MLP.
__global__ __launch_bounds__(1024) void finalize_kernel(const float* wsf, const int2* edges, int cap,
                                                        const float* __restrict__ w1,
                                                        const float* __restrict__ b1,
                                                        const float* __restrict__ w2,
                                                        const float* __restrict__ b2,
                                                        float* __restrict__ out) {
    __shared__ int lab[NROWS];
    __shared__ int tmp[NROWS];
    __shared__ int wsum[16];
    int t = threadIdx.x;
    for (int i = t; i < NROWS; i += 1024) lab[i] = i;
    unsigned int ec = ((const unsigned int*)wsf)[3];
    if (ec > (unsigned int)cap) ec = (unsigned int)cap;
    __syncthreads();

    if (ec > 0) {
        for (int it = 0; it < 16; ++it) {   // ceil(log2(8192)) + 3 = 16, as reference
            for (int i = t; i < NROWS; i += 1024) tmp[i] = lab[i];
            __syncthreads();
            for (unsigned int e = t; e < ec; e += 1024) {
                int u = edges[e].x, v = edges[e].y;
                atomicMin(&tmp[u], lab[v]);
                atomicMin(&tmp[v], lab[u]);
            }
            __syncthreads();
            for (int i = t; i < NROWS; i += 1024) lab[i] = tmp[tmp[i]];
            __syncthreads();
        }
    }

    int lc = 0;
    for (int i = t; i < NROWS; i += 1024) lc += (lab[i] == i);
    #pragma unroll
    for (int off = 32; off; off >>= 1) lc += __shfl_xor(lc, off);
    if ((t & 63) == 0) wsum[t >> 6] = lc;
    __syncthreads();

    if (t == 0) {
        int roots = 0;
        #pragma unroll
        for (int q = 0; q < 16; ++q) roots += wsum[q];
        const float n_pairs = 67100672.0f;             // 8192*8191
        float feats[4];
        feats[0] = wsf[0];
        feats[1] = wsf[1] / n_pairs;
        feats[2] = (float)((const unsigned int*)wsf)[2] / n_pairs;
        feats[3] = (float)roots / (float)NROWS;
        float acc2 = b2[0];
        for (int j = 0; j < 16; ++j) {
            float hj = b1[j];
            #pragma unroll
            for (int i = 0; i < 4; ++i) hj = fmaf(feats[i], w1[i * 16 + j], hj);
            float g = 0.5f * hj * (1.0f + erff(hj * 0.70710678118f));
            acc2 = fmaf(g, w2[j], acc2);
        }
        out[0] = 1.0f / (1.0f + expf(-acc2));
    }
}

extern "C" void kernel_launch(void* const* d_in, const int* in_sizes, int n_in,
                              void* d_out, int out_size, void* d_ws, size_t ws_size,
                              hipStream_t stream) {
    const float* cls = (const float*)d_in[0];
    const float* w1  = (const float*)d_in[1];
    const float* b1  = (const float*)d_in[2];
    const float* w2  = (const float*)d_in[3];
    const float* b2  = (const float*)d_in[4];
    float* out = (float*)d_out;

    float* wsf = (float*)d_ws;
    unsigned short* a2 = (unsigned short*)((char*)d_ws + A2_OFF);
    int2* edges = (int2*)((char*)d_ws + EDGE_OFF);
    long long avail = (long long)ws_size - (long long)EDGE_OFF;
    int cap = (int)(avail > 0 ? (avail / 8 > 4194304 ? 4194304 : avail / 8) : 0);

    prep_kernel<<<NROWS / 4, 256, 0, stream>>>(cls, a2, wsf);
    sim_kernel<<<NTRI, 256, 0, stream>>>(a2, wsf, edges, cap);
    finalize_kernel<<<1, 1024, 0, stream>>>(wsf, edges, cap, w1, b1, w2, b2, out);
}

// Round 12
// 134.776 us; speedup vs baseline: 1.1165x; 1.1165x over previous
//
#include <hip/hip_runtime.h>
#include <math.h>

// N=8192, D=256. sim = normed @ normed^T; four reductions fused, sim never materialized.
// H-only fp16: sim ~= H·H^T where H = fp16(normed). Dropped terms HL^T+LH^T+LL^T
// are bounded by ~1e-3 worst / ~3e-5 rms; rounds 2-8 dropped the ~1e-3 cross terms
// already and benched absmax 0.0, so dropping the additional 2e-7 LL^T is free.
// K=256 halves FLOPs, staging traffic, and LDS vs the [H|L] split.
#define NROWS 8192
#define DIM   256
#define K2    256                  // fp16 elems per row (512 B)
#define NTB   64                   // 8192/128 tiles per side
#define NTRI  2080                 // NTB*(NTB+1)/2 lower-tri tiles; 2080 = 8*260
#define SIM_THR 0.85f

#define A2_OFF   1024
#define EDGE_OFF (1024 + NROWS * K2 * 2)

typedef _Float16 half8 __attribute__((ext_vector_type(8)));
typedef float f32x4 __attribute__((ext_vector_type(4)));

__device__ inline void load_lds16(const void* g, void* l) {
    __builtin_amdgcn_global_load_lds((const __attribute__((address_space(1))) void*)g,
                                     (__attribute__((address_space(3))) void*)l, 16, 0, 0);
}

__device__ inline void atomicMaxF(float* addr, float val) {
    if (val >= 0.f) atomicMax((int*)addr, __float_as_int(val));
    else            atomicMin((unsigned int*)addr, __float_as_uint(val));
}

// One wave per row: normalize (fp32), round to fp16, write H (8192 x 256 fp16).
__global__ __launch_bounds__(256) void prep_kernel(const float* __restrict__ x,
                                                   unsigned short* __restrict__ a2,
                                                   float* wsf) {
    if (blockIdx.x == 0 && threadIdx.x == 0) {
        wsf[0] = -INFINITY; wsf[1] = 0.f;
        ((unsigned int*)wsf)[2] = 0u; ((unsigned int*)wsf)[3] = 0u;
    }
    int row  = blockIdx.x * 4 + (threadIdx.x >> 6);
    int lane = threadIdx.x & 63;
    float4 v = ((const float4*)(x + (size_t)row * DIM))[lane];
    float ss = v.x * v.x + v.y * v.y + v.z * v.z + v.w * v.w;
    #pragma unroll
    for (int off = 32; off; off >>= 1) ss += __shfl_xor(ss, off);
    float norm = fmaxf(sqrtf(ss), 1e-12f);
    float f[4] = {v.x / norm, v.y / norm, v.z / norm, v.w / norm};
    unsigned short h[4];
    #pragma unroll
    for (int j = 0; j < 4; ++j)
        h[j] = __builtin_bit_cast(unsigned short, (_Float16)f[j]);
    *(ushort4*)(a2 + (size_t)row * K2 + lane * 4) = make_ushort4(h[0], h[1], h[2], h[3]);
}

// 128x128 tile per block (lower-tri tiles), 256 threads = 4 waves (2x2), wave-tile
// 64x64, mfma_f32_16x16x32_f16, FULL-K panels in LDS (4 chunks x 16 KB per operand,
// 128 KB total). Single stage phase: each wave issues ALL 32 global_load_lds
// back-to-back (32 KB in flight per wave -> latency hidden by queue depth, not TLP),
// ONE vmcnt(0)+barrier, then a barrier-free LDS+MFMA phase. This removes the 8
// per-K-iter sync points that capped rounds 2-8 at ~380-450 TF.
// Chunk layout/swizzle identical to the r2/r5/r8-verified conflict-free scheme.
__global__ __launch_bounds__(256) void sim_kernel(const unsigned short* __restrict__ a2,
                                                  float* wsf, int2* edges, int cap) {
    int bid = blockIdx.x;
    int idx = (bid & 7) * (NTRI / 8) + (bid >> 3);   // bijective XCD swizzle (2080=8*260)
    int bi = (int)((sqrtf(8.f * idx + 1.f) - 1.f) * 0.5f);
    while ((bi + 1) * (bi + 2) / 2 <= idx) ++bi;
    while (bi * (bi + 1) / 2 > idx) --bi;
    int bj = idx - bi * (bi + 1) / 2;          // bj <= bi
    int i0 = bi * 128, j0 = bj * 128;

    __shared__ __align__(16) char As[4][128 * 128];   // 4 k-chunks x 16 KB
    __shared__ __align__(16) char Bs[4][128 * 128];
    __shared__ float sred[12];

    int t = threadIdx.x, lane = t & 63, w = t >> 6;   // w: 0..3
    int wr = w >> 1, wc = w & 1;                       // 2x2 wave grid

    f32x4 acc[4][4] = {};

    // staging: wave w stages rows [w*32, w*32+32); per chunk 4 loads (8 rows each).
    // lane i -> row +(i>>3), global 16B-slot (i&7)^(i>>3) within the chunk's 128 B
    // (inverse swizzle; LDS dest linear). Row stride now 512 B, chunk col = kc*128.
    int perm = ((lane & 7) ^ (lane >> 3)) * 16;
    const char* gA = (const char*)a2 + (size_t)(i0 + w * 32 + (lane >> 3)) * 512 + perm;
    const char* gB = (const char*)a2 + (size_t)(j0 + w * 32 + (lane >> 3)) * 512 + perm;
    int ldsW = w * 32 * 128;                           // wave's 32-row slab (4 KB)

    #pragma unroll
    for (int kc = 0; kc < 4; ++kc) {
        #pragma unroll
        for (int q = 0; q < 4; ++q) {
            load_lds16(gA + kc * 128 + q * 4096, As[kc] + ldsW + q * 1024);
            load_lds16(gB + kc * 128 + q * 4096, Bs[kc] + ldsW + q * 1024);
        }
    }
    asm volatile("s_waitcnt vmcnt(0)" ::: "memory");   // all 32 of this wave's loads
    __builtin_amdgcn_s_barrier();                      // all waves' data visible

    int rbA = (wr * 64 + (lane & 15)) * 128;           // frag row base (bytes, in-chunk)
    int rbB = (wc * 64 + (lane & 15)) * 128;
    int kx  = (lane & 7) << 4;                         // read-side XOR ((row&7)*16B)
    int kb0 = (lane >> 4) << 4;                        // k-group byte offset

    #pragma unroll
    for (int kc = 0; kc < 4; ++kc) {
        const char* A = As[kc];
        const char* B = Bs[kc];
        #pragma unroll
        for (int ks = 0; ks < 2; ++ks) {
            int kb = (ks * 64 + kb0) ^ kx;
            half8 af[4], bf[4];
            #pragma unroll
            for (int m = 0; m < 4; ++m) {
                af[m] = *(const half8*)(A + rbA + m * 2048 + kb);
                bf[m] = *(const half8*)(B + rbB + m * 2048 + kb);
            }
            #pragma unroll
            for (int m = 0; m < 4; ++m)
                #pragma unroll
                for (int n = 0; n < 4; ++n)
                    acc[m][n] = __builtin_amdgcn_mfma_f32_16x16x32_f16(af[m], bf[n], acc[m][n], 0, 0, 0);
        }
    }

    // fused epilogue: C/D layout col=lane&15, row=(lane>>4)*4+reg (m89-verified, r2-r8 proven)
    bool diagT = (bi == bj);
    float        wgt  = diagT ? 1.f : 2.f;
    unsigned int wgtu = diagT ? 1u : 2u;
    float lmax = -INFINITY, lsum = 0.f;
    unsigned int lcnt = 0;
    #pragma unroll
    for (int m = 0; m < 4; ++m) {
        #pragma unroll
        for (int n = 0; n < 4; ++n) {
            #pragma unroll
            for (int j = 0; j < 4; ++j) {
                float s = acc[m][n][j];
                int gi = i0 + wr * 64 + m * 16 + (lane >> 4) * 4 + j;
                int gj = j0 + wc * 64 + n * 16 + (lane & 15);
                if (gi != gj) {
                    lmax = fmaxf(lmax, s);
                    lsum += s;
                    if (s > SIM_THR) {
                        lcnt++;
                        unsigned int e = atomicAdd(&((unsigned int*)wsf)[3], 1u);
                        if (e < (unsigned int)cap) edges[e] = make_int2(gi, gj);
                    }
                }
            }
        }
    }
    #pragma unroll
    for (int off = 32; off; off >>= 1) {
        lmax = fmaxf(lmax, __shfl_xor(lmax, off));
        lsum += __shfl_xor(lsum, off);
        lcnt += __shfl_xor(lcnt, off);
    }
    if (lane == 0) { sred[w] = lmax; sred[4 + w] = lsum; ((unsigned int*)sred)[8 + w] = lcnt; }
    __syncthreads();
    if (t == 0) {
        float bm = fmaxf(fmaxf(sred[0], sred[1]), fmaxf(sred[2], sred[3]));
        float bs = sred[4] + sred[5] + sred[6] + sred[7];
        unsigned int bc = ((unsigned int*)sred)[8] + ((unsigned int*)sred)[9]
                        + ((unsigned int*)sred)[10] + ((unsigned int*)sred)[11];
        atomicMaxF(&wsf[0], bm);
        atomicAdd(&wsf[1], bs * wgt);
        if (bc) atomicAdd(&((unsigned int*)wsf)[2], bc * wgtu);
    }
}

// Single block: reference's exact 16-iter min-label + pointer-jump (LDS labels),
// early-exit when no edges (labels provably stay identity), then features + MLP.
__global__ __launch_bounds__(1024) void finalize_kernel(const float* wsf, const int2* edges, int cap,
                                                        const float* __restrict__ w1,
                                                        const float* __restrict__ b1,
                                                        const float* __restrict__ w2,
                                                        const float* __restrict__ b2,
                                                        float* __restrict__ out) {
    __shared__ int lab[NROWS];
    __shared__ int tmp[NROWS];
    __shared__ int wsum[16];
    int t = threadIdx.x;
    for (int i = t; i < NROWS; i += 1024) lab[i] = i;
    unsigned int ec = ((const unsigned int*)wsf)[3];
    if (ec > (unsigned int)cap) ec = (unsigned int)cap;
    __syncthreads();

    if (ec > 0) {
        for (int it = 0; it < 16; ++it) {   // ceil(log2(8192)) + 3 = 16, as reference
            for (int i = t; i < NROWS; i += 1024) tmp[i] = lab[i];
            __syncthreads();
            for (unsigned int e = t; e < ec; e += 1024) {
                int u = edges[e].x, v = edges[e].y;
                atomicMin(&tmp[u], lab[v]);
                atomicMin(&tmp[v], lab[u]);
            }
            __syncthreads();
            for (int i = t; i < NROWS; i += 1024) lab[i] = tmp[tmp[i]];
            __syncthreads();
        }
    }

    int lc = 0;
    for (int i = t; i < NROWS; i += 1024) lc += (lab[i] == i);
    #pragma unroll
    for (int off = 32; off; off >>= 1) lc += __shfl_xor(lc, off);
    if ((t & 63) == 0) wsum[t >> 6] = lc;
    __syncthreads();

    if (t == 0) {
        int roots = 0;
        #pragma unroll
        for (int q = 0; q < 16; ++q) roots += wsum[q];
        const float n_pairs = 67100672.0f;             // 8192*8191
        float feats[4];
        feats[0] = wsf[0];
        feats[1] = wsf[1] / n_pairs;
        feats[2] = (float)((const unsigned int*)wsf)[2] / n_pairs;
        feats[3] = (float)roots / (float)NROWS;
        float acc2 = b2[0];
        for (int j = 0; j < 16; ++j) {
            float hj = b1[j];
            #pragma unroll
            for (int i = 0; i < 4; ++i) hj = fmaf(feats[i], w1[i * 16 + j], hj);
            float g = 0.5f * hj * (1.0f + erff(hj * 0.70710678118f));
            acc2 = fmaf(g, w2[j], acc2);
        }
        out[0] = 1.0f / (1.0f + expf(-acc2));
    }
}

extern "C" void kernel_launch(void* const* d_in, const int* in_sizes, int n_in,
                              void* d_out, int out_size, void* d_ws, size_t ws_size,
                              hipStream_t stream) {
    const float* cls = (const float*)d_in[0];
    const float* w1  = (const float*)d_in[1];
    const float* b1  = (const float*)d_in[2];
    const float* w2  = (const float*)d_in[3];
    const float* b2  = (const float*)d_in[4];
    float* out = (float*)d_out;

    float* wsf = (float*)d_ws;
    unsigned short* a2 = (unsigned short*)((char*)d_ws + A2_OFF);
    int2* edges = (int2*)((char*)d_ws + EDGE_OFF);
    long long avail = (long long)ws_size - (long long)EDGE_OFF;
    int cap = (int)(avail > 0 ? (avail / 8 > 4194304 ? 4194304 : avail / 8) : 0);

    prep_kernel<<<NROWS / 4, 256, 0, stream>>>(cls, a2, wsf);
    sim_kernel<<<NTRI, 256, 0, stream>>>(a2, wsf, edges, cap);
    finalize_kernel<<<1, 1024, 0, stream>>>(wsf, edges, cap, w1, b1, w2, b2, out);
}